// Round 9
// baseline (815.632 us; speedup 1.0000x reference)
//
#include <hip/hip_runtime.h>

typedef _Float16 half8 __attribute__((ext_vector_type(8)));
typedef _Float16 half4 __attribute__((ext_vector_type(4)));
typedef float f32x4 __attribute__((ext_vector_type(4)));

#define TT 512
#define HH 64
#define MB 16     // real batches per block -> 128 blocks, ZERO garbage cells
#define S  106    // state row stride (halfs) = 53 dwords (odd) -> 2-way banks, free

__global__ __launch_bounds__(1024, 1)
void lstm_v9(const float* __restrict__ x,
             const float* __restrict__ W_ih,
             const float* __restrict__ W_hh,
             const float* __restrict__ b_ih,
             const float* __restrict__ b_hh,
             const float* __restrict__ W_fc,
             const float* __restrict__ b_fc,
             float* __restrict__ out)
{
    __shared__ __align__(16) _Float16 st[2][MB * S];   // 6784 B, double-buffered

    const int tid = threadIdx.x;
    const int w   = tid >> 6;      // wave 0..15: owns units 4w..4w+3
    const int l   = tid & 63;
    const int q   = l >> 4;
    const int col = l & 15;
    const int b0  = blockIdx.x * MB;

    // ---- persistent A fragments (weights), ONE tile per wave ----
    // rows r(m) = 64*(m&3) + 4w + (m>>2)  =>  lane (q,col) reg j = gate j of
    // unit u = 4w+q, batch col. All 16 cols REAL.
    half8 aw[3];
    {
        const int r = 64 * (col & 3) + 4 * w + (col >> 2);
        #pragma unroll
        for (int c = 0; c < 2; ++c) {
            const float* src = W_hh + r * HH + 32 * c + 8 * q;
            half8 v;
            #pragma unroll
            for (int j = 0; j < 8; ++j) v[j] = (_Float16)src[j];
            aw[c] = v;
        }
        half8 v = {};
        if (q == 0) {   // k=64..67 -> W_ih, k=68 -> bias
            #pragma unroll
            for (int j = 0; j < 4; ++j) v[j] = (_Float16)W_ih[r * 4 + j];
            v[4] = (_Float16)(b_ih[r] + b_hh[r]);
        }
        aw[2] = v;
    }

    // ---- init LDS: zero, then '1' slots, then x_0 ----
    {
        _Float16* p0 = &st[0][0];
        for (int i = tid; i < 2 * MB * S; i += 1024) p0[i] = (_Float16)0.f;
    }
    __syncthreads();
    if (tid < 2 * MB) st[tid >> 4][(tid & 15) * S + 68] = (_Float16)1.0f;

    float4 xnext;
    if (tid < MB) {
        const float4* xb = (const float4*)(x + (size_t)(b0 + tid) * TT * 4);
        float4 x0 = xb[0];
        half4 hx;
        hx[0] = (_Float16)x0.x; hx[1] = (_Float16)x0.y;
        hx[2] = (_Float16)x0.z; hx[3] = (_Float16)x0.w;
        *(half4*)&st[0][tid * S + 64] = hx;
        xnext = xb[1];
    }
    __syncthreads();

    float cst = 0.f;   // ONE real cell per lane: (batch col, unit 4w+q)
    const float kN = -1.4426950408889634f, kP = 2.8853900817779268f;

    #pragma unroll 2
    for (int t = 0; t < TT; ++t) {
        const int rb = t & 1, wb = rb ^ 1;
        const _Float16* sr = &st[rb][0];

        half8 bh0 = *(const half8*)&sr[col * S +      8 * q];   // k 0..31
        half8 bh1 = *(const half8*)&sr[col * S + 32 + 8 * q];   // k 32..63
        half8 bx  = *(const half8*)&sr[col * S + 64];           // broadcast; q>0 -> A=0

        // write x_{t+1}; prefetch x_{t+2} (wave 0 only)
        if (tid < MB) {
            half4 hx;
            hx[0] = (_Float16)xnext.x; hx[1] = (_Float16)xnext.y;
            hx[2] = (_Float16)xnext.z; hx[3] = (_Float16)xnext.w;
            *(half4*)&st[wb][tid * S + 64] = hx;
            const int tn = (t + 2 < TT) ? (t + 2) : (TT - 1);
            xnext = *(const float4*)(x + ((size_t)(b0 + tid) * TT + tn) * 4);
        }

        // chained MFMA: x/bias first, then the two h K-chunks
        const f32x4 z = {0.f, 0.f, 0.f, 0.f};
        f32x4 acc = __builtin_amdgcn_mfma_f32_16x16x32_f16(aw[2], bx,  z,   0, 0, 0);
        acc = __builtin_amdgcn_mfma_f32_16x16x32_f16(aw[0], bh0, acc, 0, 0, 0);
        acc = __builtin_amdgcn_mfma_f32_16x16x32_f16(aw[1], bh1, acc, 0, 0, 0);

        // ---- scalar cell update, shared-rcp algebra (7 trans total) ----
        // c' = (P1*c + P2) * rcp(P1*(1+EF)),  P1=(1+EI)(EG+1), P2=(EG-1)(1+EF)
        // h  = (EC-1) * rcp((1+EO)(EC+1))
        {
            const float gi = acc[0], gf = acc[1], gg = acc[2], go = acc[3];
            float EI = __builtin_amdgcn_exp2f(kN * gi);
            float EF = __builtin_amdgcn_exp2f(kN * gf);
            float EG = __builtin_amdgcn_exp2f(kP * gg);
            float P1 = (1.f + EI) * (EG + 1.f);
            float F1 = 1.f + EF;
            float r  = __builtin_amdgcn_rcpf(P1 * F1);
            float c2 = fmaf(P1, cst, (EG - 1.f) * F1) * r;
            cst = c2;
            float EO = __builtin_amdgcn_exp2f(kN * go);
            float EC = __builtin_amdgcn_exp2f(kP * c2);
            float r2 = __builtin_amdgcn_rcpf((1.f + EO) * (EC + 1.f));
            float hn = (EC - 1.f) * r2;
            st[wb][col * S + 4 * w + q] = (_Float16)hn;
        }
        __syncthreads();
    }

    // ---- FC epilogue: final h in st[0] (TT even) ----
    if (tid < MB * 4) {
        const int b = tid >> 2, o = tid & 3;
        float s = b_fc[o];
        const float* wf = W_fc + o * HH;
        #pragma unroll
        for (int k = 0; k < HH; ++k)
            s = fmaf((float)st[0][b * S + k], wf[k], s);
        out[(size_t)(b0 + b) * 4 + o] = s;
    }
}

extern "C" void kernel_launch(void* const* d_in, const int* in_sizes, int n_in,
                              void* d_out, int out_size, void* d_ws, size_t ws_size,
                              hipStream_t stream) {
    const float* x    = (const float*)d_in[0];
    const float* W_ih = (const float*)d_in[1];
    const float* W_hh = (const float*)d_in[2];
    const float* b_ih = (const float*)d_in[3];
    const float* b_hh = (const float*)d_in[4];
    const float* W_fc = (const float*)d_in[5];
    const float* b_fc = (const float*)d_in[6];
    float* out = (float*)d_out;
    lstm_v9<<<2048 / MB, 1024, 0, stream>>>(x, W_ih, W_hh, b_ih, b_hh, W_fc, b_fc, out);
}

// Round 10
// 458.821 us; speedup vs baseline: 1.7777x; 1.7777x over previous
//
#include <hip/hip_runtime.h>

typedef _Float16 half8 __attribute__((ext_vector_type(8)));
typedef _Float16 half4 __attribute__((ext_vector_type(4)));
typedef float f32x4 __attribute__((ext_vector_type(4)));

#define TT 512
#define HH 64
#define MB 16     // batches per block (M dim of tile) -> 128 blocks, zero garbage
#define S  106    // state row stride (halfs) = 53 dwords (odd) -> <=2-way banks

__global__ __launch_bounds__(256, 1)
void lstm_v10(const float* __restrict__ x,
              const float* __restrict__ W_ih,
              const float* __restrict__ W_hh,
              const float* __restrict__ b_ih,
              const float* __restrict__ b_hh,
              const float* __restrict__ W_fc,
              const float* __restrict__ b_fc,
              float* __restrict__ out)
{
    __shared__ __align__(16) _Float16 st[2][MB * S];   // 6784 B, double-buffered
    // row b of st = [h[b][0..63] | x[b][0..3] | 1 | zeros...]

    const int tid = threadIdx.x;
    const int w   = tid >> 6;      // wave 0..3: owns units 16w..16w+15
    const int l   = tid & 63;
    const int q   = l >> 4;
    const int col = l & 15;
    const int b0  = blockIdx.x * MB;
    const int u   = 16 * w + col;  // this lane's unit

    // ---- persistent B fragments: weights. Tile s (gate s): n=col -> row r=64s+u.
    // B layout: lane (q,col) holds B[k=8q+j][n=col].
    half8 bw[4][3];
    #pragma unroll
    for (int s = 0; s < 4; ++s) {
        const int r = 64 * s + u;
        #pragma unroll
        for (int c = 0; c < 2; ++c) {
            const float* src = W_hh + r * HH + 32 * c + 8 * q;
            half8 v;
            #pragma unroll
            for (int j = 0; j < 8; ++j) v[j] = (_Float16)src[j];
            bw[s][c] = v;
        }
        half8 v = {};
        if (q == 0) {   // k=64..67 -> W_ih row r, k=68 -> bias; k>=72 rows are zero
            #pragma unroll
            for (int j = 0; j < 4; ++j) v[j] = (_Float16)W_ih[r * 4 + j];
            v[4] = (_Float16)(b_ih[r] + b_hh[r]);
        }
        bw[s][2] = v;
    }

    // ---- init LDS: zero both buffers, '1' at +68 (persistent), x_0 ----
    {
        _Float16* p0 = &st[0][0];
        for (int i = tid; i < 2 * MB * S; i += 256) p0[i] = (_Float16)0.f;
    }
    __syncthreads();
    if (tid < 2 * MB) st[tid >> 4][(tid & 15) * S + 68] = (_Float16)1.0f;

    // x staging: 4 lanes per wave (l<4), batch sb = 4w+l -> no single-wave convoy
    const int  sb     = 4 * w + (l & 3);
    const bool xlane  = (l < 4);
    const float* xbp  = x + (size_t)(b0 + sb) * TT * 4;
    float4 xnext;
    if (xlane) {
        float4 x0 = *(const float4*)xbp;
        half4 hx;
        hx[0] = (_Float16)x0.x; hx[1] = (_Float16)x0.y;
        hx[2] = (_Float16)x0.z; hx[3] = (_Float16)x0.w;
        *(half4*)&st[0][sb * S + 64] = hx;
        xnext = *(const float4*)(xbp + 4);
    }
    __syncthreads();

    float cst[4] = {0.f, 0.f, 0.f, 0.f};   // cells: batch 4q+j, unit u — ALL REAL
    const float kN = -1.4426950408889634f, kP = 2.8853900817779268f;

    #pragma unroll 2
    for (int t = 0; t < TT; ++t) {
        const int rb = t & 1, wb = rb ^ 1;
        const _Float16* sr = &st[rb][0];

        // A fragments (shared by all 4 tiles): A[m=col][k=8q+j] = state[batch col][k]
        half8 ah0 = *(const half8*)&sr[col * S +      8 * q];   // k 0..31
        half8 ah1 = *(const half8*)&sr[col * S + 32 + 8 * q];   // k 32..63
        half8 ax  = *(const half8*)&sr[col * S + 64];           // bcast; q>0 -> B=0

        // stage x_{t+1} into write buffer; prefetch x_{t+2}
        if (xlane) {
            half4 hx;
            hx[0] = (_Float16)xnext.x; hx[1] = (_Float16)xnext.y;
            hx[2] = (_Float16)xnext.z; hx[3] = (_Float16)xnext.w;
            *(half4*)&st[wb][sb * S + 64] = hx;
            const int tn = (t + 2 < TT) ? (t + 2) : (TT - 1);
            xnext = *(const float4*)(xbp + tn * 4);
        }

        // 4 gate-tiles, chained over the 3 K-chunks; tiles independent -> ILP
        const f32x4 z = {0.f, 0.f, 0.f, 0.f};
        f32x4 acc[4];
        #pragma unroll
        for (int s = 0; s < 4; ++s) {
            f32x4 a = __builtin_amdgcn_mfma_f32_16x16x32_f16(bw[s][2] /*A=*/, ax, z, 0, 0, 0);
            // NOTE: operands are (A, B, C); A = state frags, B = weight frags:
            a = __builtin_amdgcn_mfma_f32_16x16x32_f16(ah0, bw[s][0],
                __builtin_amdgcn_mfma_f32_16x16x32_f16(ax, bw[s][2], z, 0, 0, 0), 0, 0, 0);
            a = __builtin_amdgcn_mfma_f32_16x16x32_f16(ah1, bw[s][1], a, 0, 0, 0);
            acc[s] = a;
        }

        // ---- 4 all-real cells per lane: batch 4q+j, unit u ----
        #pragma unroll
        for (int j = 0; j < 4; ++j) {
            const float gi = acc[0][j], gf = acc[1][j], gg = acc[2][j], go = acc[3][j];
            float EI = __builtin_amdgcn_exp2f(kN * gi);
            float EF = __builtin_amdgcn_exp2f(kN * gf);
            float EG = __builtin_amdgcn_exp2f(kP * gg);
            float P1 = (1.f + EI) * (EG + 1.f);
            float F1 = 1.f + EF;
            float r  = __builtin_amdgcn_rcpf(P1 * F1);
            float c2 = fmaf(P1, cst[j], (EG - 1.f) * F1) * r;
            cst[j] = c2;
            float EO = __builtin_amdgcn_exp2f(kN * go);
            float EC = __builtin_amdgcn_exp2f(kP * c2);
            float r2 = __builtin_amdgcn_rcpf((1.f + EO) * (EC + 1.f));
            float hn = (EC - 1.f) * r2;
            st[wb][(4 * q + j) * S + u] = (_Float16)hn;   // <=2-way banks
        }
        __syncthreads();
    }

    // ---- FC epilogue: final h in st[0] (TT even) ----
    if (tid < MB * 4) {
        const int b = tid >> 2, o = tid & 3;
        float s = b_fc[o];
        const float* wf = W_fc + o * HH;
        #pragma unroll
        for (int k = 0; k < HH; ++k)
            s = fmaf((float)st[0][b * S + k], wf[k], s);
        out[(size_t)(b0 + b) * 4 + o] = s;
    }
}

extern "C" void kernel_launch(void* const* d_in, const int* in_sizes, int n_in,
                              void* d_out, int out_size, void* d_ws, size_t ws_size,
                              hipStream_t stream) {
    const float* x    = (const float*)d_in[0];
    const float* W_ih = (const float*)d_in[1];
    const float* W_hh = (const float*)d_in[2];
    const float* b_ih = (const float*)d_in[3];
    const float* b_hh = (const float*)d_in[4];
    const float* W_fc = (const float*)d_in[5];
    const float* b_fc = (const float*)d_in[6];
    float* out = (float*)d_out;
    lstm_v10<<<2048 / MB, 256, 0, stream>>>(x, W_ih, W_hh, b_ih, b_hh, W_fc, b_fc, out);
}

// Round 11
// 268.617 us; speedup vs baseline: 3.0364x; 1.7081x over previous
//
#include <hip/hip_runtime.h>

typedef _Float16 half8 __attribute__((ext_vector_type(8)));
typedef _Float16 half4 __attribute__((ext_vector_type(4)));
typedef _Float16 half2v __attribute__((ext_vector_type(2)));
typedef float f32x4 __attribute__((ext_vector_type(4)));
typedef float f32x2 __attribute__((ext_vector_type(2)));

#define TT 512
#define HH 64
#define MB 8      // real batches per block -> 256 blocks (cols 8..15 garbage-contained)
#define S  72     // state row stride (halfs): h only; 144B rows, 16B-aligned b128 reads
#define XS 2056   // xbuf per-batch stride (halfs): 512*4 + 8 pad -> banks 4b mod 32

__device__ __forceinline__ f32x2 exp2v(f32x2 v) {
    f32x2 r;
    r.x = __builtin_amdgcn_exp2f(v.x);
    r.y = __builtin_amdgcn_exp2f(v.y);
    return r;
}
__device__ __forceinline__ f32x2 rcpv(f32x2 v) {
    f32x2 r;
    r.x = __builtin_amdgcn_rcpf(v.x);
    r.y = __builtin_amdgcn_rcpf(v.y);
    return r;
}

__global__ __launch_bounds__(512, 1)
void lstm_v11(const float* __restrict__ x,
              const float* __restrict__ W_ih,
              const float* __restrict__ W_hh,
              const float* __restrict__ b_ih,
              const float* __restrict__ b_hh,
              const float* __restrict__ W_fc,
              const float* __restrict__ b_fc,
              float* __restrict__ out)
{
    __shared__ __align__(16) _Float16 st[2][16 * S];     // 4608 B: h state, dbuf
    __shared__ __align__(16) _Float16 xbuf[MB * XS];     // 32896 B: ALL x, staged once

    const int tid = threadIdx.x;
    const int w   = tid >> 6;      // wave 0..7
    const int l   = tid & 63;
    const int q   = l >> 4;
    const int col = l & 15;
    const int b0  = blockIdx.x * MB;

    // ---- persistent A fragments (weights), 2 tiles per wave ----
    // tile p of wave w covers gate-rows r(m) = 64*(m&3) + 8w + 2*(m>>2) + p
    // => lane (q,col) reg j = gate j of unit u = 8w + 2q + p
    half8 aw[2][3];
    #pragma unroll
    for (int p = 0; p < 2; ++p) {
        const int r = 64 * (col & 3) + 8 * w + 2 * (col >> 2) + p;
        #pragma unroll
        for (int c = 0; c < 2; ++c) {
            const float* src = W_hh + r * HH + 32 * c + 8 * q;
            half8 v;
            #pragma unroll
            for (int j = 0; j < 8; ++j) v[j] = (_Float16)src[j];
            aw[p][c] = v;
        }
        half8 v = {};
        if (q == 0) {   // k=64..67 -> W_ih, k=68 -> bias (B supplies 1.0 at k=68)
            #pragma unroll
            for (int j = 0; j < 4; ++j) v[j] = (_Float16)W_ih[r * 4 + j];
            v[4] = (_Float16)(b_ih[r] + b_hh[r]);
        }
        aw[p][2] = v;
    }

    // ---- pre-stage ALL x for this block's 8 batches into LDS (f16) ----
    // 4096 (b,t) pairs / 512 threads = 8 iters; coalesced float4 reads
    #pragma unroll
    for (int it = 0; it < (MB * TT) / 512; ++it) {
        const int task = tid + it * 512;
        const int b = task >> 9, t = task & 511;
        float4 v = *(const float4*)(x + ((size_t)(b0 + b) * TT + t) * 4);
        half4 hx;
        hx[0] = (_Float16)v.x; hx[1] = (_Float16)v.y;
        hx[2] = (_Float16)v.z; hx[3] = (_Float16)v.w;
        *(half4*)&xbuf[b * XS + t * 4] = hx;
    }

    // ---- zero h state (both buffers, all 16 rows) ----
    {
        _Float16* p0 = &st[0][0];
        for (int i = tid; i < 2 * 16 * S; i += 512) p0[i] = (_Float16)0.f;
    }
    __syncthreads();

    f32x2 cst = {0.f, 0.f};        // cells p=0,1 (units 8w+2q+p, batch col)
    const int xcol = (col & 7);    // garbage cols broadcast a real batch's x
    const float kN = -1.4426950408889634f, kP = 2.8853900817779268f;

    #pragma unroll 4
    for (int t = 0; t < TT; ++t) {
        const int rb = t & 1, wb = rb ^ 1;
        const _Float16* sr = &st[rb][0];

        half8 bh0 = *(const half8*)&sr[col * S +      8 * q];   // k 0..31
        half8 bh1 = *(const half8*)&sr[col * S + 32 + 8 * q];   // k 32..63

        // x/bias B-frag: only q=0 lanes meaningful (A zero for k>=72).
        // [x0..x3, 1, 0, 0, 0] — tail is loop-invariant constant regs.
        half4 xv = *(const half4*)&xbuf[xcol * XS + t * 4];
        half8 bx = {xv[0], xv[1], xv[2], xv[3],
                    (_Float16)1.0f, (_Float16)0.f, (_Float16)0.f, (_Float16)0.f};

        // chained MFMA (x/bias chunk first), 2 independent tiles
        const f32x4 z = {0.f, 0.f, 0.f, 0.f};
        f32x4 acc0 = __builtin_amdgcn_mfma_f32_16x16x32_f16(aw[0][2], bx,  z,    0, 0, 0);
        f32x4 acc1 = __builtin_amdgcn_mfma_f32_16x16x32_f16(aw[1][2], bx,  z,    0, 0, 0);
        acc0 = __builtin_amdgcn_mfma_f32_16x16x32_f16(aw[0][0], bh0, acc0, 0, 0, 0);
        acc1 = __builtin_amdgcn_mfma_f32_16x16x32_f16(aw[1][0], bh0, acc1, 0, 0, 0);
        acc0 = __builtin_amdgcn_mfma_f32_16x16x32_f16(aw[0][1], bh1, acc0, 0, 0, 0);
        acc1 = __builtin_amdgcn_mfma_f32_16x16x32_f16(aw[1][1], bh1, acc1, 0, 0, 0);

        // ---- packed 2-cell update (shared-rcp algebra) ----
        {
            const f32x2 gi = {acc0[0], acc1[0]};
            const f32x2 gf = {acc0[1], acc1[1]};
            const f32x2 gg = {acc0[2], acc1[2]};
            const f32x2 go = {acc0[3], acc1[3]};

            f32x2 EI = exp2v(kN * gi);
            f32x2 EF = exp2v(kN * gf);
            f32x2 EG = exp2v(kP * gg);
            f32x2 rF = rcpv(1.f + EF);
            f32x2 r1 = rcpv((1.f + EI) * (EG + 1.f));
            cst = cst * rF + (EG - 1.f) * r1;

            f32x2 EO = exp2v(kN * go);
            f32x2 EC = exp2v(kP * cst);
            f32x2 r2 = rcpv((1.f + EO) * (EC + 1.f));
            f32x2 hn = (EC - 1.f) * r2;

            half2v hv = __builtin_bit_cast(half2v,
                            __builtin_amdgcn_cvt_pkrtz(hn.x, hn.y));
            *(half2v*)&st[wb][col * S + 8 * w + 2 * q] = hv;   // 4B, 2-way banks: free
        }
        __syncthreads();
    }

    // ---- FC epilogue: final h in st[0] (TT even) ----
    if (tid < MB * 4) {
        const int b = tid >> 2, o = tid & 3;
        float s = b_fc[o];
        const float* wf = W_fc + o * HH;
        #pragma unroll
        for (int k = 0; k < HH; ++k)
            s = fmaf((float)st[0][b * S + k], wf[k], s);
        out[(size_t)(b0 + b) * 4 + o] = s;
    }
}

extern "C" void kernel_launch(void* const* d_in, const int* in_sizes, int n_in,
                              void* d_out, int out_size, void* d_ws, size_t ws_size,
                              hipStream_t stream) {
    const float* x    = (const float*)d_in[0];
    const float* W_ih = (const float*)d_in[1];
    const float* W_hh = (const float*)d_in[2];
    const float* b_ih = (const float*)d_in[3];
    const float* b_hh = (const float*)d_in[4];
    const float* W_fc = (const float*)d_in[5];
    const float* b_fc = (const float*)d_in[6];
    float* out = (float*)d_out;
    lstm_v11<<<2048 / MB, 512, 0, stream>>>(x, W_ih, W_hh, b_ih, b_hh, W_fc, b_fc, out);
}